// Round 1
// baseline (187.818 us; speedup 1.0000x reference)
//
#include <hip/hip_runtime.h>
#include <hip/hip_bf16.h>
#include <math.h>

#define S_LEN 2048
#define N1 16
#define D 128
#define H 8
#define DI 128
#define K_SEL 512
#define SCALE_F 0.08838834764831845f  /* 1/sqrt(128) */
#define EPS_F 1e-9f

__global__ __launch_bounds__(256)
void sli_kl_kernel(const float* __restrict__ query,
                   const float* __restrict__ key,
                   const float* __restrict__ qidx,
                   const float* __restrict__ kidx,
                   const float* __restrict__ weights,
                   const int* __restrict__ sidx,
                   const float* __restrict__ smax,
                   const float* __restrict__ ssum,
                   float* __restrict__ out) {
  const int t = blockIdx.x;
  const int tid = threadIdx.x;
  const int lane = tid & 63;
  const int wid = tid >> 6;

  __shared__ float a_lds[K_SEL];
  __shared__ float e_lds[K_SEL];
  __shared__ float red[5][4];

  // Block-uniform row pointers (scalar-load friendly).
  const float4* qrow = (const float4*)(query + (size_t)t * N1 * D);
  const float4* qirow = (const float4*)(qidx + (size_t)t * H * DI);

  // ---------- Phase A: per selected column, all 24 dot products ----------
  for (int k = tid; k < K_SEL; k += 256) {
    const int s = sidx[t * K_SEL + k];
    const float4* kp = (const float4*)(key + (size_t)s * D);
    const float4* kip = (const float4*)(kidx + (size_t)s * DI);

    float accp[N1];
    float acci[H];
#pragma unroll
    for (int n = 0; n < N1; ++n) accp[n] = 0.f;
#pragma unroll
    for (int h = 0; h < H; ++h) acci[h] = 0.f;

    for (int d4 = 0; d4 < D / 4; ++d4) {
      const float4 kv = kp[d4];
      const float4 kiv = kip[d4];
#pragma unroll
      for (int n = 0; n < N1; ++n) {
        const float4 qv = qrow[n * (D / 4) + d4];
        accp[n] += qv.x * kv.x + qv.y * kv.y + qv.z * kv.z + qv.w * kv.w;
      }
#pragma unroll
      for (int h = 0; h < H; ++h) {
        const float4 qv = qirow[h * (DI / 4) + d4];
        acci[h] += qv.x * kiv.x + qv.y * kiv.y + qv.z * kiv.z + qv.w * kiv.w;
      }
    }

    float pa = 0.f;
#pragma unroll
    for (int n = 0; n < N1; ++n) {
      const float m = smax[n * S_LEN + t];
      const float l = ssum[n * S_LEN + t];
      pa += __expf(accp[n] * SCALE_F - m) / l;
    }
    float ia = 0.f;
#pragma unroll
    for (int h = 0; h < H; ++h) {
      const float w = weights[t * H + h];
      ia += w * fmaxf(acci[h], 0.f);
    }
    a_lds[k] = pa;
    e_lds[k] = ia;
  }
  __syncthreads();

  // ---------- Phase B: row reductions ----------
  // Pass 1: S_a = sum a, M = max e
  float la = 0.f, le = -INFINITY;
  for (int k = tid; k < K_SEL; k += 256) {
    la += a_lds[k];
    le = fmaxf(le, e_lds[k]);
  }
#pragma unroll
  for (int off = 32; off >= 1; off >>= 1) {
    la += __shfl_xor(la, off);
    le = fmaxf(le, __shfl_xor(le, off));
  }
  if (lane == 0) { red[0][wid] = la; red[1][wid] = le; }
  __syncthreads();
  const float S_a = red[0][0] + red[0][1] + red[0][2] + red[0][3];
  const float M = fmaxf(fmaxf(red[1][0], red[1][1]), fmaxf(red[1][2], red[1][3]));
  const float inv_sa = 1.f / (S_a + EPS_F);

  // Pass 2: Z = sum exp(e - M); T1 = sum pn*log(pn+eps); T2 = sum pn*e
  float z = 0.f, t1 = 0.f, t2 = 0.f;
  for (int k = tid; k < K_SEL; k += 256) {
    const float e = e_lds[k];
    const float pa = a_lds[k];
    z += __expf(e - M);
    const float pn = pa * inv_sa;
    t1 += pn * __logf(pn + EPS_F);
    t2 += pn * e;
  }
#pragma unroll
  for (int off = 32; off >= 1; off >>= 1) {
    z += __shfl_xor(z, off);
    t1 += __shfl_xor(t1, off);
    t2 += __shfl_xor(t2, off);
  }
  if (lane == 0) { red[2][wid] = z; red[3][wid] = t1; red[4][wid] = t2; }
  __syncthreads();

  if (tid == 0) {
    const float Z = red[2][0] + red[2][1] + red[2][2] + red[2][3];
    const float T1 = red[3][0] + red[3][1] + red[3][2] + red[3][3];
    const float T2 = red[4][0] + red[4][1] + red[4][2] + red[4][3];
    const float total_pn = S_a * inv_sa;
    const float kl_row = T1 - T2 + (M + __logf(Z)) * total_pn;
    atomicAdd(out, kl_row * (1.0f / (float)S_LEN));
  }
}

extern "C" void kernel_launch(void* const* d_in, const int* in_sizes, int n_in,
                              void* d_out, int out_size, void* d_ws, size_t ws_size,
                              hipStream_t stream) {
  const float* query = (const float*)d_in[0];
  const float* key = (const float*)d_in[1];
  const float* qidx = (const float*)d_in[2];
  const float* kidx = (const float*)d_in[3];
  const float* weights = (const float*)d_in[4];
  const int* sidx = (const int*)d_in[5];
  const float* smax = (const float*)d_in[6];
  const float* ssum = (const float*)d_in[7];
  float* out = (float*)d_out;

  hipMemsetAsync(out, 0, sizeof(float), stream);
  sli_kl_kernel<<<dim3(S_LEN), dim3(256), 0, stream>>>(
      query, key, qidx, kidx, weights, sidx, smax, ssum, out);
}